// Round 1
// baseline (515.608 us; speedup 1.0000x reference)
//
#include <hip/hip_runtime.h>
#include <math.h>

// Problem constants (from reference): B=512, N=600, H=256, K=9, WIN=129
#define BB   512
#define NN   600
#define HH   256
#define KS   9
#define WIN  129
#define PADW 4
#define PWIN 137           // WIN + 2*PAD
#define NP   608           // N + 2*PAD

// One block per batch element. 256 threads (4 waves).
// score[w] = (Q·K_w  +  sum_{c,k} qc[c][k]*pos[c][w+k] + qb) / 16
// where qc[c][k] = sum_h Q[h]*conv_w[h][c][k]  (conv folded into 19 scalars).
__global__ __launch_bounds__(256) void attn_kernel(
    const float* __restrict__ tokens,       // (B,N,H)
    const float* __restrict__ token_keys,   // (B,H,N)
    const int*   __restrict__ num_tokens,   // (B,)
    const float* __restrict__ query,        // (B,H)
    const float* __restrict__ alignment,    // (B,NP)
    const float* __restrict__ cum_align,    // (B,NP)
    const int*   __restrict__ window_start, // (B,)
    const float* __restrict__ conv_w,       // (H,2,K)
    const float* __restrict__ conv_b,       // (H,)
    float* __restrict__ out)
{
  const int b    = blockIdx.x;
  const int t    = threadIdx.x;
  const int lane = t & 63;
  const int wv   = t >> 6;

  __shared__ float sq[HH];          // query row
  __shared__ float p0[PWIN];        // cum/1.5 - 1
  __shared__ float p1[PWIN];        // last*2 - 1
  __shared__ float wred[4 * 19];    // per-wave partials for qc/qb
  __shared__ float w128red[4];      // per-wave partials for w=128 dot
  __shared__ float sqc[19];         // qc0[9], qc1[9], qb
  __shared__ float part[256];       // score h-half partials
  __shared__ float salign[WIN];     // scores -> exp -> normalized align
  __shared__ int   cand[WIN];       // argmax candidates
  __shared__ float s_m, s_sum;
  __shared__ int   s_arg;

  const int ws = window_start[b];
  const int nt = num_tokens[b];

  // ---- Phase A: query row, position features, conv->scalar fold ----
  const float q = query[b * HH + t];
  sq[t] = q;
  if (t < PWIN) {
    float cw = cum_align[b * NP + ws + t];
    float lw = alignment[b * NP + ws + t];
    p0[t] = cw * (1.0f / 1.5f) - 1.0f;
    p1[t] = lw * 2.0f - 1.0f;
  }
  {
    float acc[19];
    const float* cwp = conv_w + t * 18;   // (H,2,K) row for h=t, 18 contiguous
    #pragma unroll
    for (int j = 0; j < 18; ++j) acc[j] = q * cwp[j];
    acc[18] = q * conv_b[t];
    #pragma unroll
    for (int j = 0; j < 19; ++j) {
      float v = acc[j];
      #pragma unroll
      for (int off = 32; off; off >>= 1) v += __shfl_xor(v, off, 64);
      if (lane == 0) wred[wv * 19 + j] = v;
    }
  }
  __syncthreads();
  if (t < 19) sqc[t] = wred[t] + wred[19 + t] + wred[38 + t] + wred[57 + t];

  // ---- Phase B: key-dot partials. t = half*128 + w, 128-long h dot each ----
  const float* Kb = token_keys + (size_t)b * (HH * NN);
  {
    const int w    = t & 127;
    const int half = t >> 7;
    const float* Kp  = Kb + (size_t)(half * 128) * NN + ws + w;
    const float* sqp = sq + half * 128;
    float s = 0.f;
    #pragma unroll 16
    for (int h = 0; h < 128; ++h) s += sqp[h] * Kp[(size_t)h * NN];
    part[t] = s;
  }
  { // w = 128 column: block-wide reduce, thread t owns h=t
    float v = sq[t] * Kb[(size_t)t * NN + ws + 128];
    #pragma unroll
    for (int off = 32; off; off >>= 1) v += __shfl_xor(v, off, 64);
    if (lane == 0) w128red[wv] = v;
  }
  __syncthreads();

  // ---- Score assembly (threads 0..128) ----
  float sc = 0.f;
  if (t < WIN) {
    float dot = (t < 128) ? (part[t] + part[t + 128])
                          : (w128red[0] + w128red[1] + w128red[2] + w128red[3]);
    float f = sqc[18];  // qb
    #pragma unroll
    for (int k = 0; k < KS; ++k) f += sqc[k] * p0[t + k] + sqc[9 + k] * p1[t + k];
    sc = (dot + f) * 0.0625f;                 // / sqrt(256)
    if (ws + t >= nt) sc = -INFINITY;         // mask (never fires by construction)
    salign[t] = sc;
  }
  __syncthreads();

  // ---- Softmax max (wave 0) ----
  if (t < 64) {
    float m0 = fmaxf(salign[t], salign[t + 64]);
    if (t == 0) m0 = fmaxf(m0, salign[128]);
    #pragma unroll
    for (int off = 32; off; off >>= 1) m0 = fmaxf(m0, __shfl_xor(m0, off, 64));
    if (t == 0) s_m = m0;
  }
  __syncthreads();
  if (t < WIN) {
    float e = expf(sc - s_m);
    salign[t] = e;
    cand[t] = (sc == s_m) ? t : 0x7fffffff;   // first-index argmax of max score
  }
  __syncthreads();
  if (t < 64) {
    float s0 = salign[t] + salign[t + 64] + ((t == 0) ? salign[128] : 0.f);
    int   c0 = min(cand[t], cand[t + 64]);
    if (t == 0) c0 = min(c0, cand[128]);
    #pragma unroll
    for (int off = 32; off; off >>= 1) {
      s0 += __shfl_xor(s0, off, 64);
      c0 = min(c0, __shfl_xor(c0, off, 64));
    }
    if (t == 0) { s_sum = s0; s_arg = c0; }
  }
  __syncthreads();
  const float inv = 1.0f / s_sum;
  if (t < WIN) salign[t] *= inv;
  __syncthreads();

  // ---- Output pointers ----
  float* out0 = out;                       // context     (B,H)
  float* out1 = out0 + BB * HH;            // unpadded    (B,N)
  float* out2 = out1 + BB * NN;            // full_align  (B,NP)
  float* out3 = out2 + BB * NP;            // cum+align   (B,NP)
  float* out4 = out3 + BB * NP;            // new_start   (B,) as float

  // ---- Phase C: context[h=t] = sum_w align[w]*tokens[b, ws+w, t] ----
  {
    const float* Tp = tokens + (size_t)b * (NN * HH) + (size_t)ws * HH + t;
    float ctx = 0.f;
    #pragma unroll 16
    for (int w = 0; w < 128; ++w) ctx += salign[w] * Tp[(size_t)w * HH];
    ctx += salign[128] * Tp[(size_t)128 * HH];
    out0[b * HH + t] = ctx;
  }

  // ---- Scatter outputs (fully initialize: d_out is poisoned) ----
  #pragma unroll
  for (int r = 0; r < 3; ++r) {
    int i = t + r * 256;
    if (i < NN) {
      float v = (i >= ws && i <= ws + 128) ? salign[i - ws] : 0.f;
      out1[b * NN + i] = v;
    }
  }
  #pragma unroll
  for (int r = 0; r < 3; ++r) {
    int j = t + r * 256;
    if (j < NP) {
      float v = (j >= ws + PADW && j <= ws + PADW + 128) ? salign[j - ws - PADW] : 0.f;
      out2[b * NP + j] = v;
      out3[b * NP + j] = v + cum_align[b * NP + j];
    }
  }
  if (t == 0) {
    int jstar = ws + PADW + s_arg;      // position in full_align
    int ns = jstar - (PWIN / 2);        // - 68
    ns = max(ws, ns);
    ns = min(ns, nt - WIN);
    ns = max(ns, 0);
    out4[b] = (float)ns;
  }
}

extern "C" void kernel_launch(void* const* d_in, const int* in_sizes, int n_in,
                              void* d_out, int out_size, void* d_ws, size_t ws_size,
                              hipStream_t stream) {
  const float* tokens       = (const float*)d_in[0];
  // d_in[1] = tokens_mask (bool) — recomputed from num_tokens, unused
  const float* token_keys   = (const float*)d_in[2];
  const int*   num_tokens   = (const int*)d_in[3];
  const float* query        = (const float*)d_in[4];
  const float* alignment    = (const float*)d_in[5];
  const float* cum_align    = (const float*)d_in[6];
  const int*   window_start = (const int*)d_in[7];
  const float* conv_w       = (const float*)d_in[8];
  const float* conv_b       = (const float*)d_in[9];

  attn_kernel<<<BB, 256, 0, stream>>>(tokens, token_keys, num_tokens, query,
                                      alignment, cum_align, window_start,
                                      conv_w, conv_b, (float*)d_out);
}

// Round 2
// 512.226 us; speedup vs baseline: 1.0066x; 1.0066x over previous
//
#include <hip/hip_runtime.h>
#include <math.h>

// Problem constants: B=512, N=600, H=256, K=9, WIN=129
#define BB   512
#define NN   600
#define HH   256
#define KS   9
#define WIN  129
#define PADW 4
#define PWIN 137           // WIN + 2*PAD
#define NP   608           // N + 2*PAD

// One block per batch. 1024 threads = 16 waves; __launch_bounds__(1024,8)
// caps VGPR at 64 so 2 blocks/CU -> 32 waves/CU (full occupancy).
__global__ __launch_bounds__(1024, 8) void attn_kernel(
    const float* __restrict__ tokens,       // (B,N,H)
    const float* __restrict__ token_keys,   // (B,H,N)
    const int*   __restrict__ num_tokens,   // (B,)
    const float* __restrict__ query,        // (B,H)
    const float* __restrict__ alignment,    // (B,NP)
    const float* __restrict__ cum_align,    // (B,NP)
    const int*   __restrict__ window_start, // (B,)
    const float* __restrict__ conv_w,       // (H,2,K)
    const float* __restrict__ conv_b,       // (H,)
    float* __restrict__ out)
{
  const int b    = blockIdx.x;
  const int t    = threadIdx.x;
  const int lane = t & 63;
  const int wv   = t >> 6;            // wave id 0..15

  __shared__ float sq[HH];            // query row
  __shared__ float p0[PWIN], p1[PWIN];
  __shared__ float wred[4 * 19];      // conv-fold per-wave partials
  __shared__ float w128red[4];        // w=128 column dot partials
  __shared__ float sqc[19];           // folded conv scalars
  __shared__ float sS[8][130];        // per-h-group score partials (padded)
  __shared__ float salign[WIN];
  __shared__ int   cand[WIN];
  __shared__ __align__(16) float sctx[16][HH];  // 16 KB context partials
  __shared__ float s_m, s_sum;
  __shared__ int   s_arg;

  const int ws = window_start[b];
  const int nt = num_tokens[b];
  const float* Kb = token_keys + (size_t)b * (HH * NN);

  // ---- Phase A (waves 0..3): query row, position feats, conv fold, w=128 col ----
  if (t < HH) {
    const float q = query[b * HH + t];
    sq[t] = q;
    {
      float acc[19];
      const float* cwp = conv_w + t * 18;
      #pragma unroll
      for (int j = 0; j < 18; ++j) acc[j] = q * cwp[j];
      acc[18] = q * conv_b[t];
      #pragma unroll
      for (int j = 0; j < 19; ++j) {
        float v = acc[j];
        #pragma unroll
        for (int off = 32; off; off >>= 1) v += __shfl_xor(v, off, 64);
        if (lane == 0) wred[wv * 19 + j] = v;
      }
    }
    { // w = 128 column: thread t owns h=t
      float v = q * Kb[(size_t)t * NN + ws + 128];
      #pragma unroll
      for (int off = 32; off; off >>= 1) v += __shfl_xor(v, off, 64);
      if (lane == 0) w128red[wv] = v;
    }
  }
  if (t < PWIN) {
    p0[t] = cum_align[b * NP + ws + t] * (1.0f / 1.5f) - 1.0f;
    p1[t] = alignment[b * NP + ws + t] * 2.0f - 1.0f;
  }
  __syncthreads();
  if (t < 19) sqc[t] = wred[t] + wred[19 + t] + wred[38 + t] + wred[57 + t];

  // ---- Phase B: scores. wave v = (hh 0..7, wseg 0..1); 32-long h dot each ----
  {
    const int hh   = wv & 7;          // h group: rows hh*32 .. hh*32+31
    const int wseg = wv >> 3;         // w half
    const int w    = wseg * 64 + lane;     // 0..127
    const float* Kp  = Kb + (size_t)(hh * 32) * NN + ws + w;
    const float* sqp = sq + hh * 32;
    float acc = 0.f;
    #pragma unroll 8
    for (int h = 0; h < 32; ++h) acc += sqp[h] * Kp[(size_t)h * NN];
    sS[hh][w] = acc;
  }
  __syncthreads();

  // ---- Score assembly (threads 0..128) ----
  float sc = 0.f;
  if (t < WIN) {
    float dot;
    if (t < 128) {
      dot = 0.f;
      #pragma unroll
      for (int g = 0; g < 8; ++g) dot += sS[g][t];
    } else {
      dot = w128red[0] + w128red[1] + w128red[2] + w128red[3];
    }
    float f = sqc[18];
    #pragma unroll
    for (int k = 0; k < KS; ++k) f += sqc[k] * p0[t + k] + sqc[9 + k] * p1[t + k];
    sc = (dot + f) * 0.0625f;                 // / sqrt(256)
    if (ws + t >= nt) sc = -INFINITY;
    salign[t] = sc;
  }
  __syncthreads();

  // ---- Softmax max (wave 0) ----
  if (t < 64) {
    float m0 = fmaxf(salign[t], salign[t + 64]);
    if (t == 0) m0 = fmaxf(m0, salign[128]);
    #pragma unroll
    for (int off = 32; off; off >>= 1) m0 = fmaxf(m0, __shfl_xor(m0, off, 64));
    if (t == 0) s_m = m0;
  }
  __syncthreads();
  if (t < WIN) {
    float e = expf(sc - s_m);
    salign[t] = e;
    cand[t] = (sc == s_m) ? t : 0x7fffffff;   // first-index argmax
  }
  __syncthreads();
  if (t < 64) {
    float s0 = salign[t] + salign[t + 64] + ((t == 0) ? salign[128] : 0.f);
    int   c0 = min(cand[t], cand[t + 64]);
    if (t == 0) c0 = min(c0, cand[128]);
    #pragma unroll
    for (int off = 32; off; off >>= 1) {
      s0 += __shfl_xor(s0, off, 64);
      c0 = min(c0, __shfl_xor(c0, off, 64));
    }
    if (t == 0) { s_sum = s0; s_arg = c0; }
  }
  __syncthreads();
  const float inv = 1.0f / s_sum;
  if (t < WIN) salign[t] *= inv;
  __syncthreads();

  // ---- Output pointers ----
  float* out0 = out;                       // context     (B,H)
  float* out1 = out0 + BB * HH;            // unpadded    (B,N)
  float* out2 = out1 + BB * NN;            // full_align  (B,NP)
  float* out3 = out2 + BB * NP;            // cum+align   (B,NP)
  float* out4 = out3 + BB * NP;            // new_start   (B,) as float

  // ---- Phase C: context via float4. wave v covers w = v, v+16, ... ----
  {
    const float* Tb = tokens + (size_t)b * (NN * HH) + (size_t)ws * HH;
    float4 acc = make_float4(0.f, 0.f, 0.f, 0.f);
    #pragma unroll
    for (int i = 0; i < 8; ++i) {
      const int w = wv + 16 * i;            // 0..127 across waves
      const float a = salign[w];
      const float4 v4 = ((const float4*)(Tb + (size_t)w * HH))[lane];
      acc.x += a * v4.x; acc.y += a * v4.y; acc.z += a * v4.z; acc.w += a * v4.w;
    }
    if (wv == 0) {                          // tail w = 128
      const float a = salign[128];
      const float4 v4 = ((const float4*)(Tb + (size_t)128 * HH))[lane];
      acc.x += a * v4.x; acc.y += a * v4.y; acc.z += a * v4.z; acc.w += a * v4.w;
    }
    ((float4*)&sctx[wv][0])[lane] = acc;
  }
  __syncthreads();
  if (t < HH) {
    float c = 0.f;
    #pragma unroll
    for (int v = 0; v < 16; ++v) c += sctx[v][t];
    out0[b * HH + t] = c;
  }

  // ---- Scatter outputs (d_out is poisoned — write everything) ----
  if (t < NN) {
    float v = (t >= ws && t <= ws + 128) ? salign[t - ws] : 0.f;
    out1[b * NN + t] = v;
  }
  if (t < NP) {
    float v = (t >= ws + PADW && t <= ws + PADW + 128) ? salign[t - ws - PADW] : 0.f;
    out2[b * NP + t] = v;
    out3[b * NP + t] = v + cum_align[b * NP + t];
  }
  if (t == 0) {
    int jstar = ws + PADW + s_arg;
    int ns = jstar - (PWIN / 2);
    ns = max(ws, ns);
    ns = min(ns, nt - WIN);
    ns = max(ns, 0);
    out4[b] = (float)ns;
  }
}

extern "C" void kernel_launch(void* const* d_in, const int* in_sizes, int n_in,
                              void* d_out, int out_size, void* d_ws, size_t ws_size,
                              hipStream_t stream) {
  const float* tokens       = (const float*)d_in[0];
  // d_in[1] = tokens_mask (bool) — recomputed from num_tokens, unused
  const float* token_keys   = (const float*)d_in[2];
  const int*   num_tokens   = (const int*)d_in[3];
  const float* query        = (const float*)d_in[4];
  const float* alignment    = (const float*)d_in[5];
  const float* cum_align    = (const float*)d_in[6];
  const int*   window_start = (const int*)d_in[7];
  const float* conv_w       = (const float*)d_in[8];
  const float* conv_b       = (const float*)d_in[9];

  attn_kernel<<<BB, 1024, 0, stream>>>(tokens, token_keys, num_tokens, query,
                                       alignment, cum_align, window_start,
                                       conv_w, conv_b, (float*)d_out);
}